// Round 6
// baseline (54.726 us; speedup 1.0000x reference)
//
#include <hip/hip_runtime.h>
#include <hip/hip_bf16.h>

// Problem dims (fixed): B=8, Q=256, K=256, D=256, H=256, DV=512
#define B_  8
#define Q_  256
#define K_  256
#define D_  256
#define H_  256
#define DV_ 512
#define QB  4            // q-rows per attn block

#define SCALE_2LOG2E 2.8853900817779268f   // 2*log2(e): exp(2x) = 2^(x*this)
#define LOG2E_F      1.4426950408889634f

// ---------------------------------------------------------------------------
// Kernel 1: projections + exponentiation (exp factorization):
//   Eq [B][Q][H]  = 2^((queries @ W_q) * 2log2e)
//   EkT[B][H][K]  = 2^((keys    @ W_k)^T * 2log2e)   (transposed)
// 64x32 output tiles, grid (4,8,16) = 512 blocks -> 2 blocks/CU so one
// block's staging latency hides under the other's compute.
// As[d][r] (transposed A operand, b128 reads), Bs[d][c] (b64 reads).
// ---------------------------------------------------------------------------
__global__ __launch_bounds__(256) void proj_kernel(
    const float* __restrict__ queries, const float* __restrict__ keys,
    const float* __restrict__ Wq, const float* __restrict__ Wk,
    float* __restrict__ Eq, float* __restrict__ EkT) {
  const int tid = threadIdx.x;
  const int b  = blockIdx.z & 7;
  const bool kpath = blockIdx.z >= 8;
  const int rblk = blockIdx.x * 64;   // qpath: q-rows; kpath: h-rows
  const int cblk = blockIdx.y * 32;   // qpath: h-cols; kpath: k-cols

  __shared__ float As[64][68];        // [d][r]
  __shared__ float Bs[64][36];        // [d][c]

  const int lr = tid >> 4;            // 0..15
  const int lc = (tid & 15) << 2;     // 0..60 step 4
  const int brow = tid >> 2;          // 0..63 (B direct-stage d-row)
  const int bg   = tid & 3;           // 0..3  (B direct-stage col group)
  const int krow = tid >> 3;          // 0..31 (B scatter-stage k-row)
  const int dg   = tid & 7;           // 0..7  (B scatter-stage d-group)

  const int r0 = (tid & 15) << 2;     // micro-tile rows (4)
  const int c0 = (tid >> 4) << 1;     // micro-tile cols (2)

  float acc[4][2] = {};

  for (int kk = 0; kk < D_; kk += 64) {
    if (!kpath) {
      #pragma unroll
      for (int i = 0; i < 4; i++) {
        const int row = lr + i * 16;
        // As[d][q] <- queries[b][rblk+row][kk+lc+j]  (transpose scatter)
        float4 va = *(const float4*)&queries[((size_t)(b * Q_ + rblk + row)) * D_ + kk + lc];
        As[lc + 0][row] = va.x; As[lc + 1][row] = va.y;
        As[lc + 2][row] = va.z; As[lc + 3][row] = va.w;
      }
      #pragma unroll
      for (int i = 0; i < 2; i++) {
        const int g = bg + i * 4;
        // Bs[d][h] <- Wq[kk+brow][cblk+4g]  (direct float4)
        float4 vb = *(const float4*)&Wq[((size_t)(kk + brow)) * H_ + cblk + 4 * g];
        *(float4*)&Bs[brow][4 * g] = vb;
      }
    } else {
      #pragma unroll
      for (int i = 0; i < 4; i++) {
        const int row = lr + i * 16;
        // As[d][h] <- Wk[kk+row][rblk+lc]  (direct float4)
        float4 va = *(const float4*)&Wk[((size_t)(kk + row)) * H_ + rblk + lc];
        *(float4*)&As[row][lc] = va;
      }
      #pragma unroll
      for (int i = 0; i < 2; i++) {
        const int g = dg + i * 8;
        // Bs[d][k] <- keys[b][cblk+krow][kk+4g+j]  (transpose scatter)
        float4 vb = *(const float4*)&keys[((size_t)(b * K_ + cblk + krow)) * D_ + kk + 4 * g];
        Bs[4 * g + 0][krow] = vb.x; Bs[4 * g + 1][krow] = vb.y;
        Bs[4 * g + 2][krow] = vb.z; Bs[4 * g + 3][krow] = vb.w;
      }
    }
    __syncthreads();

    #pragma unroll 8
    for (int d = 0; d < 64; d++) {
      float4 av = *(const float4*)&As[d][r0];
      float2 bv = *(const float2*)&Bs[d][c0];
      acc[0][0] = fmaf(av.x, bv.x, acc[0][0]); acc[0][1] = fmaf(av.x, bv.y, acc[0][1]);
      acc[1][0] = fmaf(av.y, bv.x, acc[1][0]); acc[1][1] = fmaf(av.y, bv.y, acc[1][1]);
      acc[2][0] = fmaf(av.z, bv.x, acc[2][0]); acc[2][1] = fmaf(av.z, bv.y, acc[2][1]);
      acc[3][0] = fmaf(av.w, bv.x, acc[3][0]); acc[3][1] = fmaf(av.w, bv.y, acc[3][1]);
    }
    __syncthreads();
  }

  float* dst = kpath ? EkT : Eq;
  #pragma unroll
  for (int i = 0; i < 4; i++) {
    float2 v;
    v.x = __builtin_amdgcn_exp2f(acc[i][0] * SCALE_2LOG2E);
    v.y = __builtin_amdgcn_exp2f(acc[i][1] * SCALE_2LOG2E);
    *(float2*)&dst[((size_t)(b * 256 + rblk + r0 + i)) * 256 + cblk + c0] = v;
  }
}

// ---------------------------------------------------------------------------
// Kernel 2: fused scores + softmax + PV.
//   sigma = 1/(1 + Eq*Ek);  score' = sum_h (-2*wv[h])*sigma
// 1024 thr = 16 waves, QB=4, grid (64,8) = 512 blocks -> 2 blocks/CU.
// Score: 4-way h-split, thread owns k=tk; depth-8 register prefetch of EkT.
// Softmax: quarter qtr reduces row qq=qtr (all waves busy).
// PV: 4-way k-split x float2-dv; depth-4 register prefetch of values.
// ---------------------------------------------------------------------------
__global__ __launch_bounds__(1024) void attn_kernel(
    const float* __restrict__ Eq, const float* __restrict__ EkT,
    const float* __restrict__ wv, const float* __restrict__ values,
    float* __restrict__ out) {
  const int t   = threadIdx.x;
  const int qtr = t >> 8;       // h-quarter (score) / k-quarter (PV) / softmax row
  const int tk  = t & 255;      // owned k (score) / dv-pair (PV)
  const int b   = blockIdx.y;
  const int q0  = blockIdx.x * QB;

  __shared__ float eq_t[H_][QB];          // 4 KB  [h][qq]
  __shared__ float wv_lds[H_];            // 1 KB  (-2*wv)
  __shared__ float attn_t[K_][QB];        // 4 KB  [k][qq]
  __shared__ float scratch[6144];         // 24 KB: s2 partials (16K) / PV partials (24K)
  __shared__ float pmax[QB][4];
  __shared__ float psum[QB][4];

  // ---- stage Eq rows (transposed) + wv ----
  if (t < H_) {
    const float* qs = Eq + ((size_t)(b * Q_ + q0)) * H_ + t;
    float4 v = make_float4(qs[0], qs[H_], qs[2 * H_], qs[3 * H_]);
    *(float4*)&eq_t[t][0] = v;
    wv_lds[t] = -2.0f * wv[t];
  }
  __syncthreads();

  // ---- score partials over my 64-h quarter, k = tk; depth-8 prefetch ----
  float s2[QB] = {};
  const int hbase = qtr * 64;
  const float* kp = EkT + (size_t)b * H_ * K_ + (size_t)hbase * K_ + tk;
  float pre[8];
  #pragma unroll
  for (int i = 0; i < 8; i++) pre[i] = kp[(size_t)i * K_];
  #pragma unroll
  for (int blk = 0; blk < 64; blk += 8) {
    float cur[8];
    #pragma unroll
    for (int i = 0; i < 8; i++) cur[i] = pre[i];
    if (blk + 8 < 64) {
      #pragma unroll
      for (int i = 0; i < 8; i++) pre[i] = kp[(size_t)(blk + 8 + i) * K_];
    }
    #pragma unroll
    for (int i = 0; i < 8; i++) {
      const int h = hbase + blk + i;
      float wvh = wv_lds[h];
      float4 eq = *(const float4*)&eq_t[h][0];
      float ekv = cur[i];
      float d0 = fmaf(eq.x, ekv, 1.0f);
      float d1 = fmaf(eq.y, ekv, 1.0f);
      float d2 = fmaf(eq.z, ekv, 1.0f);
      float d3 = fmaf(eq.w, ekv, 1.0f);
      s2[0] = fmaf(wvh, __builtin_amdgcn_rcpf(d0), s2[0]);
      s2[1] = fmaf(wvh, __builtin_amdgcn_rcpf(d1), s2[1]);
      s2[2] = fmaf(wvh, __builtin_amdgcn_rcpf(d2), s2[2]);
      s2[3] = fmaf(wvh, __builtin_amdgcn_rcpf(d3), s2[3]);
    }
  }
  #pragma unroll
  for (int qq = 0; qq < QB; qq++)
    scratch[((qtr * QB + qq) << 8) + tk] = s2[qq];
  __syncthreads();

  // ---- softmax: quarter qtr owns row qq = qtr; its 4 waves cover k = tk ----
  const int wq = (t >> 6) & 3;  // wave index within quarter
  {
    const int qq = qtr;
    float sc = scratch[((0 * QB + qq) << 8) + tk] + scratch[((1 * QB + qq) << 8) + tk]
             + scratch[((2 * QB + qq) << 8) + tk] + scratch[((3 * QB + qq) << 8) + tk];
    float m = sc;
    #pragma unroll
    for (int mask = 32; mask >= 1; mask >>= 1) m = fmaxf(m, __shfl_xor(m, mask));
    if ((t & 63) == 0) pmax[qq][wq] = m;
    __syncthreads();
    float mx = fmaxf(fmaxf(pmax[qq][0], pmax[qq][1]), fmaxf(pmax[qq][2], pmax[qq][3]));
    float ev = __builtin_amdgcn_exp2f((sc - mx) * LOG2E_F);
    attn_t[tk][qq] = ev;
    float s = ev;
    #pragma unroll
    for (int mask = 32; mask >= 1; mask >>= 1) s += __shfl_xor(s, mask);
    if ((t & 63) == 0) psum[qq][wq] = s;
  }
  __syncthreads();

  float rs[QB];
  #pragma unroll
  for (int qq = 0; qq < QB; qq++)
    rs[qq] = __builtin_amdgcn_rcpf(psum[qq][0] + psum[qq][1] + psum[qq][2] + psum[qq][3]);

  // ---- PV: quarter qtr owns k in [64*qtr, +64); thread owns dv pair tk ----
  float2 acc[QB];
  #pragma unroll
  for (int qq = 0; qq < QB; qq++) acc[qq] = make_float2(0.f, 0.f);
  const float2* vp = (const float2*)(values + (size_t)b * K_ * DV_) + tk;
  const int kbase = qtr * 64;
  float2 pv[4];
  #pragma unroll
  for (int i = 0; i < 4; i++) pv[i] = vp[(size_t)(kbase + i) * (DV_ / 2)];
  #pragma unroll
  for (int kk = 0; kk < 64; kk += 4) {
    float2 cur[4];
    #pragma unroll
    for (int i = 0; i < 4; i++) cur[i] = pv[i];
    if (kk + 4 < 64) {
      #pragma unroll
      for (int i = 0; i < 4; i++) pv[i] = vp[(size_t)(kbase + kk + 4 + i) * (DV_ / 2)];
    }
    #pragma unroll
    for (int i = 0; i < 4; i++) {
      float4 a = *(const float4*)&attn_t[kbase + kk + i][0];
      acc[0].x = fmaf(a.x, cur[i].x, acc[0].x); acc[0].y = fmaf(a.x, cur[i].y, acc[0].y);
      acc[1].x = fmaf(a.y, cur[i].x, acc[1].x); acc[1].y = fmaf(a.y, cur[i].y, acc[1].y);
      acc[2].x = fmaf(a.z, cur[i].x, acc[2].x); acc[2].y = fmaf(a.z, cur[i].y, acc[2].y);
      acc[3].x = fmaf(a.w, cur[i].x, acc[3].x); acc[3].y = fmaf(a.w, cur[i].y, acc[3].y);
    }
  }
  if (qtr > 0) {
    #pragma unroll
    for (int qq = 0; qq < QB; qq++)
      ((float2*)scratch)[((qtr - 1) * QB + qq) * 256 + tk] = acc[qq];
  }
  __syncthreads();
  if (qtr == 0) {
    #pragma unroll
    for (int qq = 0; qq < QB; qq++) {
      float2 a1 = ((float2*)scratch)[(0 * QB + qq) * 256 + tk];
      float2 a2 = ((float2*)scratch)[(1 * QB + qq) * 256 + tk];
      float2 a3 = ((float2*)scratch)[(2 * QB + qq) * 256 + tk];
      float2 o;
      o.x = (acc[qq].x + a1.x + a2.x + a3.x) * rs[qq];
      o.y = (acc[qq].y + a1.y + a2.y + a3.y) * rs[qq];
      *(float2*)&out[((size_t)(b * Q_ + q0 + qq)) * DV_ + 2 * tk] = o;
    }
  }
}

extern "C" void kernel_launch(void* const* d_in, const int* in_sizes, int n_in,
                              void* d_out, int out_size, void* d_ws, size_t ws_size,
                              hipStream_t stream) {
  const float* queries = (const float*)d_in[0];  // [8,256,256]
  const float* keys    = (const float*)d_in[1];  // [8,256,256]
  const float* values  = (const float*)d_in[2];  // [8,256,512]
  const float* W_q     = (const float*)d_in[3];  // [256,256]
  const float* W_k     = (const float*)d_in[4];  // [256,256]
  const float* w_v     = (const float*)d_in[5];  // [256]
  float* out = (float*)d_out;

  float* Eq  = (float*)d_ws;                     // [8][256][256] = 2 MB
  float* EkT = Eq + (size_t)B_ * Q_ * H_;        // [8][256][256] = 2 MB

  dim3 pgrid(4, 8, 16), pblk(256);
  proj_kernel<<<pgrid, pblk, 0, stream>>>(queries, keys, W_q, W_k, Eq, EkT);

  dim3 agrid(Q_ / QB, B_), ablk(1024);
  attn_kernel<<<agrid, ablk, 0, stream>>>(Eq, EkT, w_v, values, out);
}

// Round 7
// 50.522 us; speedup vs baseline: 1.0832x; 1.0832x over previous
//
#include <hip/hip_runtime.h>
#include <hip/hip_bf16.h>

// Problem dims (fixed): B=8, Q=256, K=256, D=256, H=256, DV=512
#define B_  8
#define Q_  256
#define K_  256
#define D_  256
#define H_  256
#define DV_ 512
#define QB  4            // q-rows per attn block

#define SCALE_2LOG2E 2.8853900817779268f   // 2*log2(e): exp(2x) = 2^(x*this)
#define LOG2E_F      1.4426950408889634f

// ---------------------------------------------------------------------------
// Kernel 1: projections + exponentiation (exp factorization):
//   Eq [B][Q][H]  = 2^((queries @ W_q) * 2log2e)
//   EkT[B][H][K]  = 2^((keys    @ W_k)^T * 2log2e)   (transposed)
// Round-5 structure (measured ~8us): 64x64 tiles, grid (4,4,16),
// As[d][r] transposed so compute reads both operands as float4.
// ---------------------------------------------------------------------------
__global__ __launch_bounds__(256) void proj_kernel(
    const float* __restrict__ queries, const float* __restrict__ keys,
    const float* __restrict__ Wq, const float* __restrict__ Wk,
    float* __restrict__ Eq, float* __restrict__ EkT) {
  const int tid = threadIdx.x;
  const int m0 = blockIdx.x * 64;          // q-rows (qpath) or k-cols (kpath)
  const int h0 = blockIdx.y * 64;
  const int b  = blockIdx.z & 7;
  const bool kpath = blockIdx.z >= 8;

  __shared__ float As[64][68];             // [d][row]: qpath row=q, kpath row=h
  __shared__ float Bs[64][68];             // [d][col]: qpath col=h, kpath col=k

  const int lr = tid >> 4;                 // 0..15 (load row)
  const int lc = (tid & 15) << 2;          // 0,4,...,60 (load col, float4)
  const int r0 = (tid & 15) << 2;          // micro-tile rows
  const int c0 = (tid >> 4) << 2;          // micro-tile cols

  float acc[4][4] = {};

  for (int kk = 0; kk < D_; kk += 64) {
    if (!kpath) {
      #pragma unroll
      for (int i = 0; i < 4; i++) {
        const int row = lr + i * 16;
        float4 va = *(const float4*)&queries[((size_t)(b * Q_ + m0 + row)) * D_ + kk + lc];
        As[lc + 0][row] = va.x; As[lc + 1][row] = va.y;
        As[lc + 2][row] = va.z; As[lc + 3][row] = va.w;
        float4 vb = *(const float4*)&Wq[((size_t)(kk + row)) * H_ + h0 + lc];
        *(float4*)&Bs[row][lc] = vb;
      }
    } else {
      #pragma unroll
      for (int i = 0; i < 4; i++) {
        const int row = lr + i * 16;
        float4 va = *(const float4*)&Wk[((size_t)(kk + row)) * H_ + h0 + lc];
        *(float4*)&As[row][lc] = va;
        float4 vb = *(const float4*)&keys[((size_t)(b * K_ + m0 + row)) * D_ + kk + lc];
        Bs[lc + 0][row] = vb.x; Bs[lc + 1][row] = vb.y;
        Bs[lc + 2][row] = vb.z; Bs[lc + 3][row] = vb.w;
      }
    }
    __syncthreads();

    #pragma unroll 8
    for (int d = 0; d < 64; d++) {
      float4 av = *(const float4*)&As[d][r0];
      float4 bv = *(const float4*)&Bs[d][c0];
      acc[0][0] = fmaf(av.x, bv.x, acc[0][0]); acc[0][1] = fmaf(av.x, bv.y, acc[0][1]);
      acc[0][2] = fmaf(av.x, bv.z, acc[0][2]); acc[0][3] = fmaf(av.x, bv.w, acc[0][3]);
      acc[1][0] = fmaf(av.y, bv.x, acc[1][0]); acc[1][1] = fmaf(av.y, bv.y, acc[1][1]);
      acc[1][2] = fmaf(av.y, bv.z, acc[1][2]); acc[1][3] = fmaf(av.y, bv.w, acc[1][3]);
      acc[2][0] = fmaf(av.z, bv.x, acc[2][0]); acc[2][1] = fmaf(av.z, bv.y, acc[2][1]);
      acc[2][2] = fmaf(av.z, bv.z, acc[2][2]); acc[2][3] = fmaf(av.z, bv.w, acc[2][3]);
      acc[3][0] = fmaf(av.w, bv.x, acc[3][0]); acc[3][1] = fmaf(av.w, bv.y, acc[3][1]);
      acc[3][2] = fmaf(av.w, bv.z, acc[3][2]); acc[3][3] = fmaf(av.w, bv.w, acc[3][3]);
    }
    __syncthreads();
  }

  float* dst = kpath ? EkT : Eq;
  const int ro = kpath ? h0 : m0, co = kpath ? m0 : h0;
  #pragma unroll
  for (int i = 0; i < 4; i++) {
    float4 v;
    v.x = __builtin_amdgcn_exp2f(acc[i][0] * SCALE_2LOG2E);
    v.y = __builtin_amdgcn_exp2f(acc[i][1] * SCALE_2LOG2E);
    v.z = __builtin_amdgcn_exp2f(acc[i][2] * SCALE_2LOG2E);
    v.w = __builtin_amdgcn_exp2f(acc[i][3] * SCALE_2LOG2E);
    *(float4*)&dst[((size_t)(b * 256 + ro + r0 + i)) * 256 + co + c0] = v;
  }
}

// ---------------------------------------------------------------------------
// Kernel 2: fused scores + softmax + PV.
//   sigma = 1/(1 + Eq*Ek);  score' = sum_h (-2*wv[h])*sigma
// 1024 thr = 16 waves, QB=4; 1D grid of 512 blocks with b = blockIdx.x & 7:
// the dispatcher round-robins flat workgroup ids over the 8 XCDs, so XCD x
// sees ONLY batch x -> per-XCD L2 working set ~1 MB (EkT[b]+values[b]+Eq[b]),
// fetched from HBM once instead of 8x (FETCH_SIZE 25.6 MB -> ~8 MB).
// Score: 4-way h-split, thread owns k=tk. Softmax: quarter qtr owns row qtr.
// PV: 4-way k-split x float2-dv, LDS combine.
// ---------------------------------------------------------------------------
__global__ __launch_bounds__(1024) void attn_kernel(
    const float* __restrict__ Eq, const float* __restrict__ EkT,
    const float* __restrict__ wv, const float* __restrict__ values,
    float* __restrict__ out) {
  const int t   = threadIdx.x;
  const int qtr = t >> 8;       // h-quarter (score) / k-quarter (PV) / softmax row
  const int tk  = t & 255;      // owned k (score) / dv-pair (PV)
  const int b   = blockIdx.x & 7;           // XCD-locality decode
  const int q0  = (blockIdx.x >> 3) * QB;

  __shared__ float eq_t[H_][QB];          // 4 KB  [h][qq]
  __shared__ float wv_lds[H_];            // 1 KB  (-2*wv)
  __shared__ float attn_t[K_][QB];        // 4 KB  [k][qq]
  __shared__ float scratch[6144];         // 24 KB: s2 partials / PV partials
  __shared__ float pmax[QB][4];
  __shared__ float psum[QB][4];

  // ---- stage Eq rows (transposed) + wv ----
  if (t < H_) {
    const float* qs = Eq + ((size_t)(b * Q_ + q0)) * H_ + t;
    float4 v = make_float4(qs[0], qs[H_], qs[2 * H_], qs[3 * H_]);
    *(float4*)&eq_t[t][0] = v;
    wv_lds[t] = -2.0f * wv[t];
  }
  __syncthreads();

  // ---- score partials: s2[qq] over my 64-h quarter, k = tk ----
  float s2[QB] = {};
  const int hbase = qtr * 64;
  const float* kp = EkT + (size_t)b * H_ * K_ + (size_t)hbase * K_ + tk;
  #pragma unroll 4
  for (int hh = 0; hh < 64; hh++) {
    float ekv = kp[(size_t)hh * K_];
    float wvh = wv_lds[hbase + hh];
    float4 eq = *(const float4*)&eq_t[hbase + hh][0];
    float d0 = fmaf(eq.x, ekv, 1.0f);
    float d1 = fmaf(eq.y, ekv, 1.0f);
    float d2 = fmaf(eq.z, ekv, 1.0f);
    float d3 = fmaf(eq.w, ekv, 1.0f);
    s2[0] = fmaf(wvh, __builtin_amdgcn_rcpf(d0), s2[0]);
    s2[1] = fmaf(wvh, __builtin_amdgcn_rcpf(d1), s2[1]);
    s2[2] = fmaf(wvh, __builtin_amdgcn_rcpf(d2), s2[2]);
    s2[3] = fmaf(wvh, __builtin_amdgcn_rcpf(d3), s2[3]);
  }
  #pragma unroll
  for (int qq = 0; qq < QB; qq++)
    scratch[((qtr * QB + qq) << 8) + tk] = s2[qq];
  __syncthreads();

  // ---- softmax: quarter qtr owns row qq = qtr; its 4 waves cover k = tk ----
  const int wq = (t >> 6) & 3;  // wave index within quarter
  {
    const int qq = qtr;
    float sc = scratch[((0 * QB + qq) << 8) + tk] + scratch[((1 * QB + qq) << 8) + tk]
             + scratch[((2 * QB + qq) << 8) + tk] + scratch[((3 * QB + qq) << 8) + tk];
    float m = sc;
    #pragma unroll
    for (int mask = 32; mask >= 1; mask >>= 1) m = fmaxf(m, __shfl_xor(m, mask));
    if ((t & 63) == 0) pmax[qq][wq] = m;
    __syncthreads();
    float mx = fmaxf(fmaxf(pmax[qq][0], pmax[qq][1]), fmaxf(pmax[qq][2], pmax[qq][3]));
    float ev = __builtin_amdgcn_exp2f((sc - mx) * LOG2E_F);
    attn_t[tk][qq] = ev;
    float s = ev;
    #pragma unroll
    for (int mask = 32; mask >= 1; mask >>= 1) s += __shfl_xor(s, mask);
    if ((t & 63) == 0) psum[qq][wq] = s;
  }
  __syncthreads();

  float rs[QB];
  #pragma unroll
  for (int qq = 0; qq < QB; qq++)
    rs[qq] = __builtin_amdgcn_rcpf(psum[qq][0] + psum[qq][1] + psum[qq][2] + psum[qq][3]);

  // ---- PV: quarter qtr owns k in [64*qtr, +64); thread owns dv pair tk ----
  float2 acc[QB];
  #pragma unroll
  for (int qq = 0; qq < QB; qq++) acc[qq] = make_float2(0.f, 0.f);
  const float2* vp = (const float2*)(values + (size_t)b * K_ * DV_) + tk;
  const int kbase = qtr * 64;
  #pragma unroll 4
  for (int kk = 0; kk < 64; kk++) {
    const int k = kbase + kk;
    float2 v = vp[(size_t)k * (DV_ / 2)];
    float4 a = *(const float4*)&attn_t[k][0];
    acc[0].x = fmaf(a.x, v.x, acc[0].x); acc[0].y = fmaf(a.x, v.y, acc[0].y);
    acc[1].x = fmaf(a.y, v.x, acc[1].x); acc[1].y = fmaf(a.y, v.y, acc[1].y);
    acc[2].x = fmaf(a.z, v.x, acc[2].x); acc[2].y = fmaf(a.z, v.y, acc[2].y);
    acc[3].x = fmaf(a.w, v.x, acc[3].x); acc[3].y = fmaf(a.w, v.y, acc[3].y);
  }
  if (qtr > 0) {
    #pragma unroll
    for (int qq = 0; qq < QB; qq++)
      ((float2*)scratch)[((qtr - 1) * QB + qq) * 256 + tk] = acc[qq];
  }
  __syncthreads();
  if (qtr == 0) {
    #pragma unroll
    for (int qq = 0; qq < QB; qq++) {
      float2 a1 = ((float2*)scratch)[(0 * QB + qq) * 256 + tk];
      float2 a2 = ((float2*)scratch)[(1 * QB + qq) * 256 + tk];
      float2 a3 = ((float2*)scratch)[(2 * QB + qq) * 256 + tk];
      float2 o;
      o.x = (acc[qq].x + a1.x + a2.x + a3.x) * rs[qq];
      o.y = (acc[qq].y + a1.y + a2.y + a3.y) * rs[qq];
      *(float2*)&out[((size_t)(b * Q_ + q0 + qq)) * DV_ + 2 * tk] = o;
    }
  }
}

extern "C" void kernel_launch(void* const* d_in, const int* in_sizes, int n_in,
                              void* d_out, int out_size, void* d_ws, size_t ws_size,
                              hipStream_t stream) {
  const float* queries = (const float*)d_in[0];  // [8,256,256]
  const float* keys    = (const float*)d_in[1];  // [8,256,256]
  const float* values  = (const float*)d_in[2];  // [8,256,512]
  const float* W_q     = (const float*)d_in[3];  // [256,256]
  const float* W_k     = (const float*)d_in[4];  // [256,256]
  const float* w_v     = (const float*)d_in[5];  // [256]
  float* out = (float*)d_out;

  float* Eq  = (float*)d_ws;                     // [8][256][256] = 2 MB
  float* EkT = Eq + (size_t)B_ * Q_ * H_;        // [8][256][256] = 2 MB

  dim3 pgrid(4, 4, 16), pblk(256);
  proj_kernel<<<pgrid, pblk, 0, stream>>>(queries, keys, W_q, W_k, Eq, EkT);

  dim3 agrid(Q_ / QB * B_), ablk(1024);
  attn_kernel<<<agrid, ablk, 0, stream>>>(Eq, EkT, w_v, values, out);
}